// Round 8
// baseline (200.281 us; speedup 1.0000x reference)
//
#include <hip/hip_runtime.h>
#include <hip/hip_bf16.h>
#include <stdint.h>

// MultiHeadAttention: B=2,S=2048,D=1024,H=16,HD=64
// Pipeline: convert(f32->bf16) -> fused QKV GEMM (bf16 MFMA) -> flash attn -> out GEMM (f32 out)
// Attn: swapped-QK^T (St = mfma(K,Q)), P in registers (phi-permuted kv axis),
// double-buffered K/V staging with one barrier per KV-tile (T14 async split:
// V global->reg loads issued before compute, LDS writes after).

typedef __attribute__((ext_vector_type(8))) short bf16x8;
typedef __attribute__((ext_vector_type(4))) float f32x4;
typedef __attribute__((ext_vector_type(4))) float floatx4;
typedef __attribute__((ext_vector_type(4))) short shortx4;

#define MFMA16(a, b, c) __builtin_amdgcn_mfma_f32_16x16x32_bf16((a), (b), (c), 0, 0, 0)

static __device__ __forceinline__ short f2bf(float f) {
  __hip_bfloat16 h = __float2bfloat16(f);
  return *reinterpret_cast<short*>(&h);
}

// Bit-exact pack: lo 16 bits = bf16(a) (element 0), hi 16 bits = bf16(b).
static __device__ __forceinline__ uint32_t pack_bf16(float a, float b) {
  return (uint32_t)(uint16_t)f2bf(a) | ((uint32_t)(uint16_t)f2bf(b) << 16);
}

static __device__ __forceinline__ float fexp2(float x) {
#if __has_builtin(__builtin_amdgcn_exp2f)
  return __builtin_amdgcn_exp2f(x);
#else
  return exp2f(x);
#endif
}

static __device__ __forceinline__ void gload_lds16(const void* g, void* l) {
  __builtin_amdgcn_global_load_lds(
      (__attribute__((address_space(1))) void*)(void*)g,
      (__attribute__((address_space(3))) void*)l, 16, 0, 0);
}

// ---------------------------------------------------------------------------
// Convert inputs to bf16 workspace + concat biases.
// ---------------------------------------------------------------------------
__global__ void convert_kernel(const float* __restrict__ x,
                               const float* __restrict__ Wq, const float* __restrict__ Wk,
                               const float* __restrict__ Wv, const float* __restrict__ Wo,
                               const float* __restrict__ bq, const float* __restrict__ bk,
                               const float* __restrict__ bv,
                               __hip_bfloat16* __restrict__ xb,
                               __hip_bfloat16* __restrict__ wqkv,
                               __hip_bfloat16* __restrict__ wob,
                               float* __restrict__ bcat) {
  const int NX = (4096 * 1024) / 4;  // x quads
  const int NW = (1024 * 1024) / 4;  // per-weight quads
  const int total = NX + 4 * NW;
  for (long i = (long)blockIdx.x * blockDim.x + threadIdx.x; i < total + 768;
       i += (long)gridDim.x * blockDim.x) {
    if (i < total) {
      const float* src;
      __hip_bfloat16* dst;
      long off;
      if (i < NX)             { src = x;  dst = xb;                       off = i; }
      else if (i < NX + NW)   { src = Wq; dst = wqkv;                     off = i - NX; }
      else if (i < NX + 2*NW) { src = Wk; dst = wqkv + 1024 * 1024;       off = i - NX - NW; }
      else if (i < NX + 3*NW) { src = Wv; dst = wqkv + 2 * 1024 * 1024;   off = i - NX - 2*NW; }
      else                    { src = Wo; dst = wob;                      off = i - NX - 3*NW; }
      floatx4 v = *(const floatx4*)(src + off * 4);
      shortx4 sv;
      sv.x = f2bf(v.x); sv.y = f2bf(v.y); sv.z = f2bf(v.z); sv.w = f2bf(v.w);
      *(shortx4*)(dst + off * 4) = sv;
    } else {
      int j = (int)(i - total);  // 0..767
#pragma unroll
      for (int u = 0; u < 4; ++u) {
        int n = j * 4 + u;
        float b = (n < 1024) ? bq[n] : (n < 2048 ? bk[n - 1024] : bv[n - 2048]);
        bcat[n] = b;
      }
    }
  }
}

// ---------------------------------------------------------------------------
// GEMM: C[M,N] = (A[M,K] @ Bm[N,K]^T + bias) * scale(col)
// 128x128 tile, BK=64, 4 waves (2x2 of 64x64), global_load_lds w16,
// XOR-swizzled LDS via pre-swizzled global source addresses.
// ---------------------------------------------------------------------------
template <bool OUT_BF16>
__global__ __launch_bounds__(256, 2) void gemm_bt(const __hip_bfloat16* __restrict__ A,
                                                  const __hip_bfloat16* __restrict__ Bm,
                                                  const float* __restrict__ bias,
                                                  void* __restrict__ Cout, int M, int N, int K,
                                                  float scale, int scale_limit) {
  __shared__ __hip_bfloat16 As[128 * 64];
  __shared__ __hip_bfloat16 Bs[128 * 64];
  const int tid = threadIdx.x;
  const int lane = tid & 63;
  const int w = tid >> 6;
  const int wm = w >> 1, wn = w & 1;

  // XCD-aware swizzle (gridDim.x % 8 == 0 for all our launches)
  const int nwg = gridDim.x;
  const int bi = blockIdx.x;
  const int wg = (bi & 7) * (nwg >> 3) + (bi >> 3);
  const int MT = M >> 7;
  const int tm = wg % MT, tn = wg / MT;
  const long brow = (long)tm * 128, bcol = (long)tn * 128;

  const int srow = tid >> 3;          // staging row within 32-row pass
  const int scsw = (tid & 7) << 4;    // swizzled col-byte

  f32x4 acc[4][4] = {};

  char* lAs = (char*)As + (tid & 0xC0) * 16;  // wave-uniform base (= w*1024)
  char* lBs = (char*)Bs + (tid & 0xC0) * 16;

  for (int k0 = 0; k0 < K; k0 += 64) {
#pragma unroll
    for (int p = 0; p < 4; ++p) {
      int r = p * 32 + srow;
      int cb = scsw ^ ((r & 7) << 4);  // pre-swizzled global source
      gload_lds16(A + (brow + r) * (long)K + k0 + (cb >> 1), lAs + p * 4096);
      gload_lds16(Bm + (bcol + r) * (long)K + k0 + (cb >> 1), lBs + p * 4096);
    }
    __syncthreads();
#pragma unroll
    for (int ks = 0; ks < 2; ++ks) {
      bf16x8 af[4], bfr[4];
      const int cbase = ks * 64 + ((lane >> 4) << 4);
#pragma unroll
      for (int m = 0; m < 4; ++m) {
        int r = wm * 64 + m * 16 + (lane & 15);
        af[m] = *(const bf16x8*)((const char*)As + r * 128 + (cbase ^ ((r & 7) << 4)));
      }
#pragma unroll
      for (int n = 0; n < 4; ++n) {
        int r = wn * 64 + n * 16 + (lane & 15);
        bfr[n] = *(const bf16x8*)((const char*)Bs + r * 128 + (cbase ^ ((r & 7) << 4)));
      }
#pragma unroll
      for (int m = 0; m < 4; ++m)
#pragma unroll
        for (int n = 0; n < 4; ++n) acc[m][n] = MFMA16(af[m], bfr[n], acc[m][n]);
    }
    __syncthreads();
  }

#pragma unroll
  for (int n = 0; n < 4; ++n) {
    const long col = bcol + wn * 64 + n * 16 + (lane & 15);
    const float bv = bias[col];
    const float sc = (col < scale_limit) ? scale : 1.0f;
#pragma unroll
    for (int m = 0; m < 4; ++m) {
      const long row0 = brow + wm * 64 + m * 16 + ((lane >> 4) << 2);
#pragma unroll
      for (int j = 0; j < 4; ++j) {
        float v = (acc[m][n][j] + bv) * sc;
        if (OUT_BF16)
          ((__hip_bfloat16*)Cout)[(row0 + j) * N + col] = __float2bfloat16(v);
        else
          ((float*)Cout)[(row0 + j) * N + col] = v;
      }
    }
  }
}

// ---------------------------------------------------------------------------
// Flash attention, swapped-QK^T / in-register-P, double-buffered K/V.
// qkv: [4096, 3072] bf16 (Q|K|V per row, head-major cols of 64).
// Q pre-scaled by 0.125*log2(e). O: [4096, 1024] bf16.
// Grid: 512 = (qtile 16) x (head 16) x (batch 2). 4 waves x 32 q-rows.
//
// kv-axis permutation phi(kv) = 32*(n>>1) + 8*g + 4*(n&1) + j
//   (kv = 16n + 4g + j). P's A-fragment slot order and Vt's column order
// both use phi, so the contraction stays consistent with zero cross-lane ops.
//
// Per tile t: issue K(t+1) gload_lds + V(t+1) global->reg loads, compute tile t
// (QK with kf hoisted across both m-subtiles, softmax, PV), ds_write V(t+1)
// into the idle buffer, ONE barrier. Writes always target buf^1 while reads
// hit buf; tile t+2 writes vs tile t reads are separated by the barrier.
// ---------------------------------------------------------------------------
__global__ __launch_bounds__(256, 2) void attn_kernel(const __hip_bfloat16* __restrict__ qkv,
                                                      __hip_bfloat16* __restrict__ O) {
  __shared__ __hip_bfloat16 Ks[2][128 * 64];   // [kv][64], 128B rows, XOR-swizzled
  __shared__ __hip_bfloat16 Vt[2][64 * 128];   // [d][phi(kv)], 256B rows, XOR-swizzled

  const int tid = threadIdx.x;
  const int lane = tid & 63;
  const int w = tid >> 6;
  const int g = lane >> 4;     // 16-lane group
  const int t = lane & 15;     // lane-in-group: q-row (softmax) / d-col (PV C)
  const int bi = blockIdx.x;
  const int qt = bi & 15, hh = (bi >> 4) & 15, bb = bi >> 8;
  const long rowQ0 = (long)bb * 2048 + qt * 128;
  const long rowK0 = (long)bb * 2048;
  const int qcol = hh * 64, kcol = 1024 + hh * 64, vcol = 2048 + hh * 64;

  // Q fragments (B-operand of swapped QK): col=q=t, k-chunk = ks*32 + g*8
  bf16x8 qf[2][2];
#pragma unroll
  for (int m = 0; m < 2; ++m)
#pragma unroll
    for (int ks = 0; ks < 2; ++ks) {
      long r = rowQ0 + w * 32 + m * 16 + t;
      int c = qcol + ks * 32 + g * 8;
      qf[m][ks] = *(const bf16x8*)(qkv + r * 3072 + c);
    }

  f32x4 acc_o[2][4] = {};
  float mrun[2] = {-1e30f, -1e30f}, lrun[2] = {0.f, 0.f};
  uint32_t cpk[2][8][2];  // packed bf16 P-pairs: [m][n][h], pair kv = 16n+4g+2h

  // broadcast source base: lane (g, t'=g*4+j) within same group
  const int sb = (lane & 48) | ((lane & 48) >> 2);

  const int srow = tid >> 3;
  const int scsw = (tid & 7) << 4;
  const int vr = tid >> 1;          // kv row this thread stages for V
  const int vc0 = (tid & 1) * 32;   // d base
  // phi decomposition for the staged kv row (constant per thread)
  const int vphib = 4 * (vr >> 5) + ((vr >> 2) & 3);       // 16B block idx
  const int vinb = ((vr >> 4) & 1) * 8 + (vr & 3) * 2;     // byte within block

  bf16x8 vreg[4];

  // --- prologue: stage tile 0 ---
#pragma unroll
  for (int p = 0; p < 4; ++p) {
    int r = p * 32 + srow;
    int cb = scsw ^ ((r & 7) << 4);
    gload_lds16(qkv + (rowK0 + r) * 3072 + kcol + (cb >> 1),
                (char*)(&Ks[0][0]) + (tid & 0xC0) * 16 + p * 4096);
  }
#pragma unroll
  for (int u = 0; u < 4; ++u)
    vreg[u] = *(const bf16x8*)(qkv + (rowK0 + vr) * 3072 + vcol + vc0 + u * 8);
#pragma unroll
  for (int u = 0; u < 4; ++u)
#pragma unroll
    for (int e = 0; e < 8; ++e) {
      int d = vc0 + u * 8 + e;
      *(short*)((char*)(&Vt[0][0]) + d * 256 + ((vphib ^ (d & 15)) << 4) + vinb) = vreg[u][e];
    }
  __syncthreads();

  int cur = 0;
  for (int tt = 0; tt < 16; ++tt) {
    // --- issue next tile's loads (K -> LDS buf^1 async, V -> regs) ---
    if (tt < 15) {
      const long kvn = (long)(tt + 1) * 128;
#pragma unroll
      for (int p = 0; p < 4; ++p) {
        int r = p * 32 + srow;
        int cb = scsw ^ ((r & 7) << 4);
        gload_lds16(qkv + (rowK0 + kvn + r) * 3072 + kcol + (cb >> 1),
                    (char*)(&Ks[cur ^ 1][0]) + (tid & 0xC0) * 16 + p * 4096);
      }
#pragma unroll
      for (int u = 0; u < 4; ++u)
        vreg[u] = *(const bf16x8*)(qkv + (rowK0 + kvn + vr) * 3072 + vcol + vc0 + u * 8);
    }

    const char* KsCur = (const char*)(&Ks[cur][0]);
    const char* VtCur = (const char*)(&Vt[cur][0]);

    // --- St = K.Q^T (kf read once, used for both m-subtiles) ---
    f32x4 s[2][8] = {};  // s[m][n][j] = S[q=m*16+t][kv=16n+4g+j]
#pragma unroll
    for (int ks = 0; ks < 2; ++ks) {
      const int cbase = ks * 64 + g * 16;
#pragma unroll
      for (int n = 0; n < 8; ++n) {
        const int r = n * 16 + t;
        const bf16x8 kf = *(const bf16x8*)(KsCur + r * 128 + (cbase ^ ((r & 7) << 4)));
        s[0][n] = MFMA16(kf, qf[0][ks], s[0][n]);
        s[1][n] = MFMA16(kf, qf[1][ks], s[1][n]);
      }
    }

    // --- online softmax + pack P (per m) ---
#pragma unroll
    for (int m = 0; m < 2; ++m) {
      float mx = s[m][0][0];
#pragma unroll
      for (int n = 0; n < 8; ++n)
#pragma unroll
        for (int j = 0; j < 4; ++j) mx = fmaxf(mx, s[m][n][j]);
      mx = fmaxf(mx, __shfl_xor(mx, 16));
      mx = fmaxf(mx, __shfl_xor(mx, 32));
      const float newm = fmaxf(mrun[m], mx);
      const float corr = fexp2(mrun[m] - newm);
      mrun[m] = newm;
      float rs = 0.f;
#pragma unroll
      for (int n = 0; n < 8; ++n)
#pragma unroll
        for (int j = 0; j < 4; ++j) {
          float p = fexp2(s[m][n][j] - newm);
          s[m][n][j] = p;
          rs += p;
        }
      rs += __shfl_xor(rs, 16);
      rs += __shfl_xor(rs, 32);
      lrun[m] = lrun[m] * corr + rs;
      // rescale acc_o[m]: corr lives at lane (g, t=g*4+j) -> broadcast per row j
#pragma unroll
      for (int j = 0; j < 4; ++j) {
        float cj = __shfl(corr, sb | j);
#pragma unroll
        for (int nd = 0; nd < 4; ++nd) acc_o[m][nd][j] *= cj;
      }
      // pack P into bf16 pairs (kv pair = 16n+4g+{2h,2h+1}); bit-exact manual pack
#pragma unroll
      for (int n = 0; n < 8; ++n) {
        cpk[m][n][0] = pack_bf16(s[m][n][0], s[m][n][1]);
        cpk[m][n][1] = pack_bf16(s[m][n][2], s[m][n][3]);
      }
    }

    // --- O += P.V over phi-ordered kv (4 k-steps of 32) ---
#pragma unroll
    for (int ks = 0; ks < 4; ++ks) {
      bf16x8 vf[4];
#pragma unroll
      for (int nd = 0; nd < 4; ++nd) {
        int d = nd * 16 + t;
        vf[nd] = *(const bf16x8*)(VtCur + d * 256 + (((4 * ks + g) ^ t) << 4));
      }
#pragma unroll
      for (int m = 0; m < 2; ++m) {
        union { bf16x8 v; uint32_t u[4]; } au;
        au.u[0] = cpk[m][2 * ks][0];
        au.u[1] = cpk[m][2 * ks][1];
        au.u[2] = cpk[m][2 * ks + 1][0];
        au.u[3] = cpk[m][2 * ks + 1][1];
#pragma unroll
        for (int nd = 0; nd < 4; ++nd) acc_o[m][nd] = MFMA16(au.v, vf[nd], acc_o[m][nd]);
      }
    }

    // --- write next tile's V into the idle buffer, then one barrier ---
    if (tt < 15) {
      char* VtNxt = (char*)(&Vt[cur ^ 1][0]);
#pragma unroll
      for (int u = 0; u < 4; ++u)
#pragma unroll
        for (int e = 0; e < 8; ++e) {
          int d = vc0 + u * 8 + e;
          *(short*)(VtNxt + d * 256 + ((vphib ^ (d & 15)) << 4) + vinb) = vreg[u][e];
        }
      __syncthreads();
      cur ^= 1;
    }
  }

  // --- epilogue: O /= l (broadcast per row), store bf16 ---
#pragma unroll
  for (int m = 0; m < 2; ++m) {
    const float inv = 1.0f / lrun[m];
#pragma unroll
    for (int j = 0; j < 4; ++j) {
      const float ij = __shfl(inv, sb | j);
      const long r = rowQ0 + w * 32 + m * 16 + g * 4 + j;
#pragma unroll
      for (int nd = 0; nd < 4; ++nd) {
        O[r * 1024 + qcol + nd * 16 + t] = __float2bfloat16(acc_o[m][nd][j] * ij);
      }
    }
  }
}

// ---------------------------------------------------------------------------
extern "C" void kernel_launch(void* const* d_in, const int* in_sizes, int n_in,
                              void* d_out, int out_size, void* d_ws, size_t ws_size,
                              hipStream_t stream) {
  const float* x  = (const float*)d_in[0];
  const float* Wq = (const float*)d_in[1];
  const float* bq = (const float*)d_in[2];
  const float* Wk = (const float*)d_in[3];
  const float* bk = (const float*)d_in[4];
  const float* Wv = (const float*)d_in[5];
  const float* bv = (const float*)d_in[6];
  const float* Wo = (const float*)d_in[7];
  const float* bo = (const float*)d_in[8];

  __hip_bfloat16* ws = (__hip_bfloat16*)d_ws;
  __hip_bfloat16* xb   = ws;
  __hip_bfloat16* wqkv = xb + (size_t)4096 * 1024;
  __hip_bfloat16* wob  = wqkv + (size_t)3072 * 1024;
  __hip_bfloat16* qkvb = wob + (size_t)1024 * 1024;
  __hip_bfloat16* ob   = qkvb + (size_t)4096 * 3072;
  float* bcat = (float*)(ob + (size_t)4096 * 1024);

  // 0.125 (1/sqrt(HD)) * log2(e), folded into Q so attention uses exp2 directly
  const float qscale = 0.18033688011112042f;

  convert_kernel<<<dim3(2048), dim3(256), 0, stream>>>(x, Wq, Wk, Wv, Wo, bq, bk, bv,
                                                       xb, wqkv, wob, bcat);
  gemm_bt<true><<<dim3(768), dim3(256), 0, stream>>>(xb, wqkv, bcat, (void*)qkvb,
                                                     4096, 3072, 1024, qscale, 1024);
  attn_kernel<<<dim3(512), dim3(256), 0, stream>>>(qkvb, ob);
  gemm_bt<false><<<dim3(256), dim3(256), 0, stream>>>(ob, wob, bo, d_out,
                                                      4096, 1024, 1024, 1.0f, 0);
}